// Round 1
// baseline (561.231 us; speedup 1.0000x reference)
//
#include <hip/hip_runtime.h>

// ---------------- helpers ----------------
__device__ __forceinline__ float rl(float v, int l) {
    return __int_as_float(__builtin_amdgcn_readlane(__float_as_int(v), l));
}

__device__ __forceinline__ int lowerb(const int* a, int n, int v) {
    int lo = 0, hi = n;
    while (lo < hi) { int m = (lo + hi) >> 1; if (a[m] < v) lo = m + 1; else hi = m; }
    return lo;
}

// ---------------- kernels ----------------
__global__ void k_zero_i32(int* __restrict__ p, int n) {
    int i = blockIdx.x * blockDim.x + threadIdx.x;
    if (i < n) p[i] = 0;
}

__global__ void k_hist(const int* __restrict__ dst, int* __restrict__ deg, int E) {
    int e = blockIdx.x * blockDim.x + threadIdx.x;
    if (e < E) atomicAdd(&deg[dst[e]], 1);
}

// single block: exclusive scan of deg -> off, cur; also dinv = rsqrt(deg+1)
__global__ __launch_bounds__(1024) void k_scan(const int* __restrict__ deg,
        int* __restrict__ off, int* __restrict__ cur, float* __restrict__ dinv, int N) {
    __shared__ int ps[1024];
    int t = threadIdx.x;
    int chunk = (N + 1023) / 1024;
    int b = t * chunk;
    int e = min(b + chunk, N);
    int s = 0;
    for (int i = b; i < e; ++i) s += deg[i];
    ps[t] = s;
    __syncthreads();
    for (int d = 1; d < 1024; d <<= 1) {
        int v = (t >= d) ? ps[t - d] : 0;
        __syncthreads();
        ps[t] += v;
        __syncthreads();
    }
    int run = ps[t] - s;  // exclusive prefix
    for (int i = b; i < e; ++i) {
        off[i] = run;
        cur[i] = run;
        dinv[i] = rsqrtf((float)deg[i] + 1.0f);
        run += deg[i];
    }
    if (b < N && e == N) off[N] = run;
}

__global__ void k_scatter(const int* __restrict__ src, const int* __restrict__ dst,
        int* __restrict__ cur, int* __restrict__ ssrc, int E) {
    int e = blockIdx.x * blockDim.x + threadIdx.x;
    if (e < E) {
        int pos = atomicAdd(&cur[dst[e]], 1);
        ssrc[pos] = src[e];
    }
}

// O = X @ W   (X: nrows x 128, W: 128 x 128 row-major)
// wave holds one 64-channel column block of W in VGPRs; x broadcast via readlane.
__global__ __launch_bounds__(256, 2) void k_gemm(const float* __restrict__ X,
        const float* __restrict__ W, float* __restrict__ O, int nrows) {
    int wave = threadIdx.x >> 6, lane = threadIdx.x & 63;
    int c = (wave & 1) * 64 + lane;   // my output channel
    float w[128];
    #pragma unroll
    for (int k = 0; k < 128; ++k) w[k] = W[k * 128 + c];

    int grp = blockIdx.x * 2 + (wave >> 1);     // row-group id (2 per block)
    int gstride = gridDim.x * 2;
    for (int r0 = grp * 2; r0 < nrows; r0 += gstride * 2) {
        int r1 = r0 + 1;
        float2 xa = *(const float2*)&X[(size_t)r0 * 128 + 2 * lane];
        float2 xb = (r1 < nrows) ? *(const float2*)&X[(size_t)r1 * 128 + 2 * lane]
                                 : make_float2(0.f, 0.f);
        float a0 = 0.f, a1 = 0.f, b0 = 0.f, b1 = 0.f;
        #pragma unroll
        for (int k = 0; k < 128; k += 2) {
            int ln = k >> 1;
            float xa0 = rl(xa.x, ln), xa1 = rl(xa.y, ln);
            float xb0 = rl(xb.x, ln), xb1 = rl(xb.y, ln);
            a0 = fmaf(xa0, w[k],     a0);
            a1 = fmaf(xa1, w[k + 1], a1);
            b0 = fmaf(xb0, w[k],     b0);
            b1 = fmaf(xb1, w[k + 1], b1);
        }
        O[(size_t)r0 * 128 + c] = a0 + a1;
        if (r1 < nrows) O[(size_t)r1 * 128 + c] = b0 + b1;
    }
}

// GCN aggregate: O[i] = relu( sum_{e: dst=i} H[src]*dinv[src]*dinv[i] + H[i]*dinv[i]^2 + bias )
// one wave per node, lane covers channels 2l, 2l+1
__global__ __launch_bounds__(256) void k_agg(const float* __restrict__ H,
        const float* __restrict__ dinv, const int* __restrict__ off,
        const int* __restrict__ ssrc, const float* __restrict__ bias,
        float* __restrict__ O, int N) {
    int lane = threadIdx.x & 63;
    int w = (blockIdx.x * blockDim.x + threadIdx.x) >> 6;
    int nw = (gridDim.x * blockDim.x) >> 6;
    float2 bv = *(const float2*)&bias[2 * lane];
    for (int i = w; i < N; i += nw) {
        int iu = __builtin_amdgcn_readfirstlane(i);
        float di = dinv[iu];
        int j0 = __builtin_amdgcn_readfirstlane(off[iu]);
        int j1 = __builtin_amdgcn_readfirstlane(off[iu + 1]);
        float2 hv = *(const float2*)&H[(size_t)iu * 128 + 2 * lane];
        float sl = di * di;
        float a0 = hv.x * sl, a1 = hv.y * sl;
        for (int j = j0; j < j1; ++j) {
            int s = __builtin_amdgcn_readfirstlane(ssrc[j]);
            float nrm = dinv[s] * di;
            float2 hs = *(const float2*)&H[(size_t)s * 128 + 2 * lane];
            a0 = fmaf(hs.x, nrm, a0);
            a1 = fmaf(hs.y, nrm, a1);
        }
        a0 += bv.x; a1 += bv.y;
        a0 = fmaxf(a0, 0.f); a1 = fmaxf(a1, 0.f);
        *(float2*)&O[(size_t)iu * 128 + 2 * lane] = make_float2(a0, a1);
    }
}

// per-graph mean pool (batch sorted): one block per graph
__global__ __launch_bounds__(128) void k_pool(const float* __restrict__ X,
        const int* __restrict__ batch, float* __restrict__ P, int N) {
    __shared__ int sb[2];
    int g = blockIdx.x;
    if (threadIdx.x == 0) {
        sb[0] = lowerb(batch, N, g);
        sb[1] = lowerb(batch, N, g + 1);
    }
    __syncthreads();
    int s = sb[0], e = sb[1];
    int c = threadIdx.x;
    float a0 = 0.f, a1 = 0.f, a2 = 0.f, a3 = 0.f;
    int n = s;
    for (; n + 3 < e; n += 4) {
        a0 += X[(size_t)n * 128 + c];
        a1 += X[(size_t)(n + 1) * 128 + c];
        a2 += X[(size_t)(n + 2) * 128 + c];
        a3 += X[(size_t)(n + 3) * 128 + c];
    }
    for (; n < e; ++n) a0 += X[(size_t)n * 128 + c];
    int cnt = e - s;
    float inv = cnt > 0 ? 1.0f / (float)cnt : 0.0f;
    P[g * 128 + c] = (a0 + a1 + a2 + a3) * inv;
}

__global__ void k_final(const float* __restrict__ P, const float* __restrict__ Wl,
        const float* __restrict__ bl, float* __restrict__ out, int G, int CO) {
    int t = blockIdx.x * blockDim.x + threadIdx.x;
    if (t >= G * CO) return;
    int g = t / CO, o = t % CO;
    float acc = bl[o];
    for (int k = 0; k < 128; ++k) acc += P[g * 128 + k] * Wl[k * CO + o];
    out[t] = acc;
}

// ---------------- launcher ----------------
extern "C" void kernel_launch(void* const* d_in, const int* in_sizes, int n_in,
                              void* d_out, int out_size, void* d_ws, size_t ws_size,
                              hipStream_t stream) {
    const float* x     = (const float*)d_in[0];
    const int*   ei    = (const int*)d_in[1];
    const int*   batch = (const int*)d_in[2];
    const float* W1e   = (const float*)d_in[5];
    const float* b1e   = (const float*)d_in[6];
    const float* W2e   = (const float*)d_in[9];
    const float* b2e   = (const float*)d_in[10];
    const float* Wlin  = (const float*)d_in[11];
    const float* blin  = (const float*)d_in[12];
    float* out = (float*)d_out;

    int N  = in_sizes[0] / 128;
    int E  = in_sizes[1] / 2;
    int CO = in_sizes[12];          // 10
    int G  = out_size / CO;         // 64

    const int* src = ei;
    const int* dst = ei + E;

    int* deg  = (int*)d_ws;                     // N
    int* off  = deg + N;                        // N+1 (padded to N+4)
    int* cur  = off + (N + 4);                  // N
    int* ssrc = cur + N;                        // E
    float* dinv   = (float*)(ssrc + E);         // N
    float* hbuf   = dinv + N;                   // N*128
    float* xbuf   = hbuf + (size_t)N * 128;     // N*128
    float* pooled = xbuf + (size_t)N * 128;     // G*128

    k_zero_i32<<<(N + 255) / 256, 256, 0, stream>>>(deg, N);
    k_hist<<<(E + 255) / 256, 256, 0, stream>>>(dst, deg, E);
    k_scan<<<1, 1024, 0, stream>>>(deg, off, cur, dinv, N);
    k_scatter<<<(E + 255) / 256, 256, 0, stream>>>(src, dst, cur, ssrc, E);

    k_gemm<<<768, 256, 0, stream>>>(x, W1e, hbuf, N);
    k_agg<<<2048, 256, 0, stream>>>(hbuf, dinv, off, ssrc, b1e, xbuf, N);
    k_gemm<<<768, 256, 0, stream>>>(xbuf, W2e, hbuf, N);
    k_agg<<<2048, 256, 0, stream>>>(hbuf, dinv, off, ssrc, b2e, xbuf, N);

    k_pool<<<G, 128, 0, stream>>>(xbuf, batch, pooled, N);
    k_final<<<3, 256, 0, stream>>>(pooled, Wlin, blin, out, G, CO);
}

// Round 2
// 432.404 us; speedup vs baseline: 1.2979x; 1.2979x over previous
//
#include <hip/hip_runtime.h>

// ---------------- helpers ----------------
__device__ __forceinline__ float rl(float v, int l) {
    return __int_as_float(__builtin_amdgcn_readlane(__float_as_int(v), l));
}

__device__ __forceinline__ int lowerb(const int* a, int n, int v) {
    int lo = 0, hi = n;
    while (lo < hi) { int m = (lo + hi) >> 1; if (a[m] < v) lo = m + 1; else hi = m; }
    return lo;
}

// ---------------- kernels ----------------
__global__ void k_zero_i32(int* __restrict__ p, int n) {
    int i = blockIdx.x * blockDim.x + threadIdx.x;
    if (i < n) p[i] = 0;
}

__global__ void k_hist(const int* __restrict__ dst, int* __restrict__ deg, int E) {
    int e = blockIdx.x * blockDim.x + threadIdx.x;
    if (e < E) atomicAdd(&deg[dst[e]], 1);
}

// phase 1: per-block inclusive scan of deg (256 elems/block) -> locscan (exclusive), bsum; dinv
__global__ __launch_bounds__(256) void k_scan1(const int* __restrict__ deg,
        int* __restrict__ locscan, int* __restrict__ bsum, float* __restrict__ dinv, int N) {
    __shared__ int sh[256];
    int t = threadIdx.x;
    int i = blockIdx.x * 256 + t;
    int d = (i < N) ? deg[i] : 0;
    sh[t] = d;
    __syncthreads();
    int v = d;
    #pragma unroll
    for (int o = 1; o < 256; o <<= 1) {
        int u = (t >= o) ? sh[t - o] : 0;
        __syncthreads();
        v += u;
        sh[t] = v;
        __syncthreads();
    }
    if (i < N) {
        locscan[i] = v - d;                 // exclusive within block
        dinv[i] = rsqrtf((float)d + 1.0f);
    }
    if (t == 255) bsum[blockIdx.x] = v;     // block total
}

// phase 2: single small block scans block sums (nb <= 256) -> boff (exclusive), off[N]=total
__global__ __launch_bounds__(256) void k_scan2(const int* __restrict__ bsum,
        int* __restrict__ boff, int* __restrict__ off, int nb, int N) {
    __shared__ int sh[256];
    int t = threadIdx.x;
    int d = (t < nb) ? bsum[t] : 0;
    sh[t] = d;
    __syncthreads();
    int v = d;
    #pragma unroll
    for (int o = 1; o < 256; o <<= 1) {
        int u = (t >= o) ? sh[t - o] : 0;
        __syncthreads();
        v += u;
        sh[t] = v;
        __syncthreads();
    }
    if (t < nb) boff[t] = v - d;
    if (t == 255) off[N] = v;               // grand total (= E)
}

// phase 3: off[i] = locscan[i] + boff[block]; cur = off
__global__ __launch_bounds__(256) void k_scan3(const int* __restrict__ locscan,
        const int* __restrict__ boff, int* __restrict__ off, int* __restrict__ cur, int N) {
    int i = blockIdx.x * 256 + threadIdx.x;
    if (i < N) {
        int v = locscan[i] + boff[blockIdx.x];
        off[i] = v;
        cur[i] = v;
    }
}

__global__ void k_scatter(const int* __restrict__ src, const int* __restrict__ dst,
        int* __restrict__ cur, int* __restrict__ ssrc, int E) {
    int e = blockIdx.x * blockDim.x + threadIdx.x;
    if (e < E) {
        int pos = atomicAdd(&cur[dst[e]], 1);
        ssrc[pos] = src[e];
    }
}

// O = X @ W   (X: nrows x 128, W: 128 x 128 row-major)
// wave holds one 64-channel column block of W in VGPRs; x broadcast via readlane.
__global__ __launch_bounds__(256, 2) void k_gemm(const float* __restrict__ X,
        const float* __restrict__ W, float* __restrict__ O, int nrows) {
    int wave = threadIdx.x >> 6, lane = threadIdx.x & 63;
    int c = (wave & 1) * 64 + lane;   // my output channel
    float w[128];
    #pragma unroll
    for (int k = 0; k < 128; ++k) w[k] = W[k * 128 + c];

    int grp = blockIdx.x * 2 + (wave >> 1);     // row-group id (2 per block)
    int gstride = gridDim.x * 2;
    for (int r0 = grp * 2; r0 < nrows; r0 += gstride * 2) {
        int r1 = r0 + 1;
        float2 xa = *(const float2*)&X[(size_t)r0 * 128 + 2 * lane];
        float2 xb = (r1 < nrows) ? *(const float2*)&X[(size_t)r1 * 128 + 2 * lane]
                                 : make_float2(0.f, 0.f);
        float a0 = 0.f, a1 = 0.f, b0 = 0.f, b1 = 0.f;
        #pragma unroll
        for (int k = 0; k < 128; k += 2) {
            int ln = k >> 1;
            float xa0 = rl(xa.x, ln), xa1 = rl(xa.y, ln);
            float xb0 = rl(xb.x, ln), xb1 = rl(xb.y, ln);
            a0 = fmaf(xa0, w[k],     a0);
            a1 = fmaf(xa1, w[k + 1], a1);
            b0 = fmaf(xb0, w[k],     b0);
            b1 = fmaf(xb1, w[k + 1], b1);
        }
        O[(size_t)r0 * 128 + c] = a0 + a1;
        if (r1 < nrows) O[(size_t)r1 * 128 + c] = b0 + b1;
    }
}

// GCN aggregate: O[i] = relu( sum_{e: dst=i} H[src]*dinv[src]*dinv[i] + H[i]*dinv[i]^2 + bias )
// one wave per node, lane covers channels 2l, 2l+1
__global__ __launch_bounds__(256) void k_agg(const float* __restrict__ H,
        const float* __restrict__ dinv, const int* __restrict__ off,
        const int* __restrict__ ssrc, const float* __restrict__ bias,
        float* __restrict__ O, int N) {
    int lane = threadIdx.x & 63;
    int w = (blockIdx.x * blockDim.x + threadIdx.x) >> 6;
    int nw = (gridDim.x * blockDim.x) >> 6;
    float2 bv = *(const float2*)&bias[2 * lane];
    for (int i = w; i < N; i += nw) {
        int iu = __builtin_amdgcn_readfirstlane(i);
        float di = dinv[iu];
        int j0 = __builtin_amdgcn_readfirstlane(off[iu]);
        int j1 = __builtin_amdgcn_readfirstlane(off[iu + 1]);
        float2 hv = *(const float2*)&H[(size_t)iu * 128 + 2 * lane];
        float sl = di * di;
        float a0 = hv.x * sl, a1 = hv.y * sl;
        for (int j = j0; j < j1; ++j) {
            int s = __builtin_amdgcn_readfirstlane(ssrc[j]);
            float nrm = dinv[s] * di;
            float2 hs = *(const float2*)&H[(size_t)s * 128 + 2 * lane];
            a0 = fmaf(hs.x, nrm, a0);
            a1 = fmaf(hs.y, nrm, a1);
        }
        a0 += bv.x; a1 += bv.y;
        a0 = fmaxf(a0, 0.f); a1 = fmaxf(a1, 0.f);
        *(float2*)&O[(size_t)iu * 128 + 2 * lane] = make_float2(a0, a1);
    }
}

// per-graph mean pool (batch sorted): one block per graph
__global__ __launch_bounds__(128) void k_pool(const float* __restrict__ X,
        const int* __restrict__ batch, float* __restrict__ P, int N) {
    __shared__ int sb[2];
    int g = blockIdx.x;
    if (threadIdx.x == 0) {
        sb[0] = lowerb(batch, N, g);
        sb[1] = lowerb(batch, N, g + 1);
    }
    __syncthreads();
    int s = sb[0], e = sb[1];
    int c = threadIdx.x;
    float a0 = 0.f, a1 = 0.f, a2 = 0.f, a3 = 0.f;
    int n = s;
    for (; n + 3 < e; n += 4) {
        a0 += X[(size_t)n * 128 + c];
        a1 += X[(size_t)(n + 1) * 128 + c];
        a2 += X[(size_t)(n + 2) * 128 + c];
        a3 += X[(size_t)(n + 3) * 128 + c];
    }
    for (; n < e; ++n) a0 += X[(size_t)n * 128 + c];
    int cnt = e - s;
    float inv = cnt > 0 ? 1.0f / (float)cnt : 0.0f;
    P[g * 128 + c] = (a0 + a1 + a2 + a3) * inv;
}

__global__ void k_final(const float* __restrict__ P, const float* __restrict__ Wl,
        const float* __restrict__ bl, float* __restrict__ out, int G, int CO) {
    int t = blockIdx.x * blockDim.x + threadIdx.x;
    if (t >= G * CO) return;
    int g = t / CO, o = t % CO;
    float acc = bl[o];
    for (int k = 0; k < 128; ++k) acc += P[g * 128 + k] * Wl[k * CO + o];
    out[t] = acc;
}

// ---------------- launcher ----------------
extern "C" void kernel_launch(void* const* d_in, const int* in_sizes, int n_in,
                              void* d_out, int out_size, void* d_ws, size_t ws_size,
                              hipStream_t stream) {
    const float* x     = (const float*)d_in[0];
    const int*   ei    = (const int*)d_in[1];
    const int*   batch = (const int*)d_in[2];
    const float* W1e   = (const float*)d_in[5];
    const float* b1e   = (const float*)d_in[6];
    const float* W2e   = (const float*)d_in[9];
    const float* b2e   = (const float*)d_in[10];
    const float* Wlin  = (const float*)d_in[11];
    const float* blin  = (const float*)d_in[12];
    float* out = (float*)d_out;

    int N  = in_sizes[0] / 128;
    int E  = in_sizes[1] / 2;
    int CO = in_sizes[12];          // 10
    int G  = out_size / CO;         // 64

    const int* src = ei;
    const int* dst = ei + E;

    int* deg  = (int*)d_ws;                     // N
    int* off  = deg + N;                        // N+1 (padded to N+4)
    int* cur  = off + (N + 4);                  // N
    int* ssrc = cur + N;                        // E
    float* dinv   = (float*)(ssrc + E);         // N
    float* hbuf   = dinv + N;                   // N*128
    float* xbuf   = hbuf + (size_t)N * 128;     // N*128
    float* pooled = xbuf + (size_t)N * 128;     // G*128
    int* locscan  = (int*)(pooled + (size_t)G * 128);  // N
    int* bsum     = locscan + N;                // 256
    int* boff     = bsum + 256;                 // 256

    int nb = (N + 255) / 256;                   // 196 for N=50000 (must be <=256)

    k_zero_i32<<<(N + 255) / 256, 256, 0, stream>>>(deg, N);
    k_hist<<<(E + 255) / 256, 256, 0, stream>>>(dst, deg, E);
    k_scan1<<<nb, 256, 0, stream>>>(deg, locscan, bsum, dinv, N);
    k_scan2<<<1, 256, 0, stream>>>(bsum, boff, off, nb, N);
    k_scan3<<<nb, 256, 0, stream>>>(locscan, boff, off, cur, N);
    k_scatter<<<(E + 255) / 256, 256, 0, stream>>>(src, dst, cur, ssrc, E);

    k_gemm<<<768, 256, 0, stream>>>(x, W1e, hbuf, N);
    k_agg<<<2048, 256, 0, stream>>>(hbuf, dinv, off, ssrc, b1e, xbuf, N);
    k_gemm<<<768, 256, 0, stream>>>(xbuf, W2e, hbuf, N);
    k_agg<<<2048, 256, 0, stream>>>(hbuf, dinv, off, ssrc, b2e, xbuf, N);

    k_pool<<<G, 128, 0, stream>>>(xbuf, batch, pooled, N);
    k_final<<<3, 256, 0, stream>>>(pooled, Wlin, blin, out, G, CO);
}

// Round 3
// 379.194 us; speedup vs baseline: 1.4801x; 1.1403x over previous
//
#include <hip/hip_runtime.h>

// ---------------- helpers ----------------
__device__ __forceinline__ float rl(float v, int l) {
    return __int_as_float(__builtin_amdgcn_readlane(__float_as_int(v), l));
}
__device__ __forceinline__ int rfl(int v) { return __builtin_amdgcn_readfirstlane(v); }

__device__ __forceinline__ int lowerb(const int* a, int n, int v) {
    int lo = 0, hi = n;
    while (lo < hi) { int m = (lo + hi) >> 1; if (a[m] < v) lo = m + 1; else hi = m; }
    return lo;
}

// ---------------- kernels ----------------
__global__ void k_zero_i32(int* __restrict__ p, int n) {
    int i = blockIdx.x * blockDim.x + threadIdx.x;
    if (i < n) p[i] = 0;
}

__global__ void k_hist(const int* __restrict__ dst, int* __restrict__ deg, int E) {
    int e = blockIdx.x * blockDim.x + threadIdx.x;
    if (e < E) atomicAdd(&deg[dst[e]], 1);
}

// phase 1: per-block inclusive scan of deg (256 elems/block) -> locscan (exclusive), bsum; dinv
__global__ __launch_bounds__(256) void k_scan1(const int* __restrict__ deg,
        int* __restrict__ locscan, int* __restrict__ bsum, float* __restrict__ dinv, int N) {
    __shared__ int sh[256];
    int t = threadIdx.x;
    int i = blockIdx.x * 256 + t;
    int d = (i < N) ? deg[i] : 0;
    sh[t] = d;
    __syncthreads();
    int v = d;
    #pragma unroll
    for (int o = 1; o < 256; o <<= 1) {
        int u = (t >= o) ? sh[t - o] : 0;
        __syncthreads();
        v += u;
        sh[t] = v;
        __syncthreads();
    }
    if (i < N) {
        locscan[i] = v - d;
        dinv[i] = rsqrtf((float)d + 1.0f);
    }
    if (t == 255) bsum[blockIdx.x] = v;
}

// phase 2: single block scans block sums (nb <= 256)
__global__ __launch_bounds__(256) void k_scan2(const int* __restrict__ bsum,
        int* __restrict__ boff, int* __restrict__ off, int nb, int N) {
    __shared__ int sh[256];
    int t = threadIdx.x;
    int d = (t < nb) ? bsum[t] : 0;
    sh[t] = d;
    __syncthreads();
    int v = d;
    #pragma unroll
    for (int o = 1; o < 256; o <<= 1) {
        int u = (t >= o) ? sh[t - o] : 0;
        __syncthreads();
        v += u;
        sh[t] = v;
        __syncthreads();
    }
    if (t < nb) boff[t] = v - d;
    if (t == 255) off[N] = v;
}

// phase 3: off[i] = locscan[i] + boff[block]; cur = off
__global__ __launch_bounds__(256) void k_scan3(const int* __restrict__ locscan,
        const int* __restrict__ boff, int* __restrict__ off, int* __restrict__ cur, int N) {
    int i = blockIdx.x * 256 + threadIdx.x;
    if (i < N) {
        int v = locscan[i] + boff[blockIdx.x];
        off[i] = v;
        cur[i] = v;
    }
}

// scatter edges into CSR; also precompute per-edge norm = dinv[src]*dinv[dst]
__global__ void k_scatter(const int* __restrict__ src, const int* __restrict__ dst,
        int* __restrict__ cur, int* __restrict__ ssrc, float* __restrict__ snrm,
        const float* __restrict__ dinv, int E) {
    int e = blockIdx.x * blockDim.x + threadIdx.x;
    if (e < E) {
        int s = src[e], d = dst[e];
        int pos = atomicAdd(&cur[d], 1);
        ssrc[pos] = s;
        snrm[pos] = dinv[s] * dinv[d];
    }
}

// O = X @ W   (X: nrows x 128, W: 128 x 128 row-major)
__global__ __launch_bounds__(256, 2) void k_gemm(const float* __restrict__ X,
        const float* __restrict__ W, float* __restrict__ O, int nrows) {
    int wave = threadIdx.x >> 6, lane = threadIdx.x & 63;
    int c = (wave & 1) * 64 + lane;
    float w[128];
    #pragma unroll
    for (int k = 0; k < 128; ++k) w[k] = W[k * 128 + c];

    int grp = blockIdx.x * 2 + (wave >> 1);
    int gstride = gridDim.x * 2;
    for (int r0 = grp * 2; r0 < nrows; r0 += gstride * 2) {
        int r1 = r0 + 1;
        float2 xa = *(const float2*)&X[(size_t)r0 * 128 + 2 * lane];
        float2 xb = (r1 < nrows) ? *(const float2*)&X[(size_t)r1 * 128 + 2 * lane]
                                 : make_float2(0.f, 0.f);
        float a0 = 0.f, a1 = 0.f, b0 = 0.f, b1 = 0.f;
        #pragma unroll
        for (int k = 0; k < 128; k += 2) {
            int ln = k >> 1;
            float xa0 = rl(xa.x, ln), xa1 = rl(xa.y, ln);
            float xb0 = rl(xb.x, ln), xb1 = rl(xb.y, ln);
            a0 = fmaf(xa0, w[k],     a0);
            a1 = fmaf(xa1, w[k + 1], a1);
            b0 = fmaf(xb0, w[k],     b0);
            b1 = fmaf(xb1, w[k + 1], b1);
        }
        O[(size_t)r0 * 128 + c] = a0 + a1;
        if (r1 < nrows) O[(size_t)r1 * 128 + c] = b0 + b1;
    }
}

// GCN aggregate with 8-deep gather pipelining.
// O[i] = relu( sum_e H[ssrc[j]]*snrm[j] + H[i]*dinv[i]^2 + bias )
__global__ __launch_bounds__(256) void k_agg(const float* __restrict__ H,
        const float* __restrict__ dinv, const int* __restrict__ off,
        const int* __restrict__ ssrc, const float* __restrict__ snrm,
        const float* __restrict__ bias, float* __restrict__ O, int N) {
    int lane = threadIdx.x & 63;
    int w = (blockIdx.x * blockDim.x + threadIdx.x) >> 6;
    int nw = (gridDim.x * blockDim.x) >> 6;
    float2 bv = *(const float2*)&bias[2 * lane];
    for (int i = w; i < N; i += nw) {
        int iu = rfl(i);
        float di = dinv[iu];
        int j0 = rfl(off[iu]);
        int j1 = rfl(off[iu + 1]);
        float2 hv = *(const float2*)&H[(size_t)iu * 128 + 2 * lane];
        float sl = di * di;
        float a0 = hv.x * sl, a1 = hv.y * sl;
        int j = j0;
        // 8-deep: issue 8 independent gathers before consuming
        for (; j + 8 <= j1; j += 8) {
            int s0 = rfl(ssrc[j]),     s1 = rfl(ssrc[j + 1]);
            int s2 = rfl(ssrc[j + 2]), s3 = rfl(ssrc[j + 3]);
            int s4 = rfl(ssrc[j + 4]), s5 = rfl(ssrc[j + 5]);
            int s6 = rfl(ssrc[j + 6]), s7 = rfl(ssrc[j + 7]);
            float2 h0 = *(const float2*)&H[(size_t)s0 * 128 + 2 * lane];
            float2 h1 = *(const float2*)&H[(size_t)s1 * 128 + 2 * lane];
            float2 h2 = *(const float2*)&H[(size_t)s2 * 128 + 2 * lane];
            float2 h3 = *(const float2*)&H[(size_t)s3 * 128 + 2 * lane];
            float2 h4 = *(const float2*)&H[(size_t)s4 * 128 + 2 * lane];
            float2 h5 = *(const float2*)&H[(size_t)s5 * 128 + 2 * lane];
            float2 h6 = *(const float2*)&H[(size_t)s6 * 128 + 2 * lane];
            float2 h7 = *(const float2*)&H[(size_t)s7 * 128 + 2 * lane];
            float n0 = __builtin_amdgcn_readfirstlane(__float_as_int(0.f)), nn;
            (void)n0; (void)nn;
            float m0 = snrm[j],     m1 = snrm[j + 1], m2 = snrm[j + 2], m3 = snrm[j + 3];
            float m4 = snrm[j + 4], m5 = snrm[j + 5], m6 = snrm[j + 6], m7 = snrm[j + 7];
            a0 = fmaf(h0.x, m0, a0); a1 = fmaf(h0.y, m0, a1);
            a0 = fmaf(h1.x, m1, a0); a1 = fmaf(h1.y, m1, a1);
            a0 = fmaf(h2.x, m2, a0); a1 = fmaf(h2.y, m2, a1);
            a0 = fmaf(h3.x, m3, a0); a1 = fmaf(h3.y, m3, a1);
            a0 = fmaf(h4.x, m4, a0); a1 = fmaf(h4.y, m4, a1);
            a0 = fmaf(h5.x, m5, a0); a1 = fmaf(h5.y, m5, a1);
            a0 = fmaf(h6.x, m6, a0); a1 = fmaf(h6.y, m6, a1);
            a0 = fmaf(h7.x, m7, a0); a1 = fmaf(h7.y, m7, a1);
        }
        for (; j + 4 <= j1; j += 4) {
            int s0 = rfl(ssrc[j]),     s1 = rfl(ssrc[j + 1]);
            int s2 = rfl(ssrc[j + 2]), s3 = rfl(ssrc[j + 3]);
            float2 h0 = *(const float2*)&H[(size_t)s0 * 128 + 2 * lane];
            float2 h1 = *(const float2*)&H[(size_t)s1 * 128 + 2 * lane];
            float2 h2 = *(const float2*)&H[(size_t)s2 * 128 + 2 * lane];
            float2 h3 = *(const float2*)&H[(size_t)s3 * 128 + 2 * lane];
            float m0 = snrm[j], m1 = snrm[j + 1], m2 = snrm[j + 2], m3 = snrm[j + 3];
            a0 = fmaf(h0.x, m0, a0); a1 = fmaf(h0.y, m0, a1);
            a0 = fmaf(h1.x, m1, a0); a1 = fmaf(h1.y, m1, a1);
            a0 = fmaf(h2.x, m2, a0); a1 = fmaf(h2.y, m2, a1);
            a0 = fmaf(h3.x, m3, a0); a1 = fmaf(h3.y, m3, a1);
        }
        for (; j < j1; ++j) {
            int s = rfl(ssrc[j]);
            float2 hs = *(const float2*)&H[(size_t)s * 128 + 2 * lane];
            float m = snrm[j];
            a0 = fmaf(hs.x, m, a0);
            a1 = fmaf(hs.y, m, a1);
        }
        a0 += bv.x; a1 += bv.y;
        a0 = fmaxf(a0, 0.f); a1 = fmaxf(a1, 0.f);
        *(float2*)&O[(size_t)iu * 128 + 2 * lane] = make_float2(a0, a1);
    }
}

// parallel partial mean-pool: sorted batch -> register accumulate, flush on graph change
__global__ __launch_bounds__(256) void k_pool_part(const float* __restrict__ X,
        const int* __restrict__ batch, float* __restrict__ pooled, int N) {
    int c = threadIdx.x & 127, sub = threadIdx.x >> 7;   // 2 rows in flight per block
    int chunk = (N + gridDim.x - 1) / gridDim.x;
    int b = blockIdx.x * chunk, e = min(b + chunk, N);
    float acc = 0.f;
    int cg = -1;
    for (int n = b + sub; n < e; n += 2) {
        int g = batch[n];
        if (g != cg) {
            if (cg >= 0) atomicAdd(&pooled[cg * 128 + c], acc);
            acc = 0.f;
            cg = g;
        }
        acc += X[(size_t)n * 128 + c];
    }
    if (cg >= 0) atomicAdd(&pooled[cg * 128 + c], acc);
}

// final: divide by per-graph count (binary search on sorted batch) and apply Wlin
__global__ void k_final(const float* __restrict__ P, const int* __restrict__ batch,
        const float* __restrict__ Wl, const float* __restrict__ bl,
        float* __restrict__ out, int G, int CO, int N) {
    int t = blockIdx.x * blockDim.x + threadIdx.x;
    if (t >= G * CO) return;
    int g = t / CO, o = t % CO;
    int cnt = lowerb(batch, N, g + 1) - lowerb(batch, N, g);
    float inv = cnt > 0 ? 1.0f / (float)cnt : 0.0f;
    float acc = bl[o];
    for (int k = 0; k < 128; ++k) acc += P[g * 128 + k] * inv * Wl[k * CO + o];
    out[t] = acc;
}

// ---------------- launcher ----------------
extern "C" void kernel_launch(void* const* d_in, const int* in_sizes, int n_in,
                              void* d_out, int out_size, void* d_ws, size_t ws_size,
                              hipStream_t stream) {
    const float* x     = (const float*)d_in[0];
    const int*   ei    = (const int*)d_in[1];
    const int*   batch = (const int*)d_in[2];
    const float* W1e   = (const float*)d_in[5];
    const float* b1e   = (const float*)d_in[6];
    const float* W2e   = (const float*)d_in[9];
    const float* b2e   = (const float*)d_in[10];
    const float* Wlin  = (const float*)d_in[11];
    const float* blin  = (const float*)d_in[12];
    float* out = (float*)d_out;

    int N  = in_sizes[0] / 128;
    int E  = in_sizes[1] / 2;
    int CO = in_sizes[12];          // 10
    int G  = out_size / CO;         // 64

    const int* src = ei;
    const int* dst = ei + E;

    int* deg  = (int*)d_ws;                     // N
    int* off  = deg + N;                        // N+1 (pad 4)
    int* cur  = off + (N + 4);                  // N
    int* ssrc = cur + N;                        // E
    float* snrm   = (float*)(ssrc + E);         // E
    float* dinv   = snrm + E;                   // N
    float* hbuf   = dinv + N;                   // N*128
    float* xbuf   = hbuf + (size_t)N * 128;     // N*128
    float* pooled = xbuf + (size_t)N * 128;     // G*128
    int* locscan  = (int*)(pooled + (size_t)G * 128);  // N
    int* bsum     = locscan + N;                // 256
    int* boff     = bsum + 256;                 // 256

    int nb = (N + 255) / 256;

    k_zero_i32<<<(N + 255) / 256, 256, 0, stream>>>(deg, N);
    k_zero_i32<<<(G * 128 + 255) / 256, 256, 0, stream>>>((int*)pooled, G * 128);
    k_hist<<<(E + 255) / 256, 256, 0, stream>>>(dst, deg, E);
    k_scan1<<<nb, 256, 0, stream>>>(deg, locscan, bsum, dinv, N);
    k_scan2<<<1, 256, 0, stream>>>(bsum, boff, off, nb, N);
    k_scan3<<<nb, 256, 0, stream>>>(locscan, boff, off, cur, N);
    k_scatter<<<(E + 255) / 256, 256, 0, stream>>>(src, dst, cur, ssrc, snrm, dinv, E);

    k_gemm<<<768, 256, 0, stream>>>(x, W1e, hbuf, N);
    k_agg<<<2048, 256, 0, stream>>>(hbuf, dinv, off, ssrc, snrm, b1e, xbuf, N);
    k_gemm<<<768, 256, 0, stream>>>(xbuf, W2e, hbuf, N);
    k_agg<<<2048, 256, 0, stream>>>(hbuf, dinv, off, ssrc, snrm, b2e, xbuf, N);

    k_pool_part<<<512, 256, 0, stream>>>(xbuf, batch, pooled, N);
    k_final<<<3, 256, 0, stream>>>(pooled, batch, Wlin, blin, out, G, CO, N);
}

// Round 4
// 346.651 us; speedup vs baseline: 1.6190x; 1.0939x over previous
//
#include <hip/hip_runtime.h>
#include <hip/hip_fp16.h>

// ---------------- helpers ----------------
__device__ __forceinline__ int rfl(int v) { return __builtin_amdgcn_readfirstlane(v); }

__device__ __forceinline__ int lowerb(const int* a, int n, int v) {
    int lo = 0, hi = n;
    while (lo < hi) { int m = (lo + hi) >> 1; if (a[m] < v) lo = m + 1; else hi = m; }
    return lo;
}

// ---------------- kernels ----------------
__global__ void k_zero_i32(int* __restrict__ p, int n) {
    int i = blockIdx.x * blockDim.x + threadIdx.x;
    if (i < n) p[i] = 0;
}

__global__ void k_hist(const int* __restrict__ dst, int* __restrict__ deg, int E) {
    int e = blockIdx.x * blockDim.x + threadIdx.x;
    if (e < E) atomicAdd(&deg[dst[e]], 1);
}

// phase 1: per-block inclusive scan of deg -> locscan (exclusive), bsum; dinv
__global__ __launch_bounds__(256) void k_scan1(const int* __restrict__ deg,
        int* __restrict__ locscan, int* __restrict__ bsum, float* __restrict__ dinv, int N) {
    __shared__ int sh[256];
    int t = threadIdx.x;
    int i = blockIdx.x * 256 + t;
    int d = (i < N) ? deg[i] : 0;
    sh[t] = d;
    __syncthreads();
    int v = d;
    #pragma unroll
    for (int o = 1; o < 256; o <<= 1) {
        int u = (t >= o) ? sh[t - o] : 0;
        __syncthreads();
        v += u;
        sh[t] = v;
        __syncthreads();
    }
    if (i < N) {
        locscan[i] = v - d;
        dinv[i] = rsqrtf((float)d + 1.0f);
    }
    if (t == 255) bsum[blockIdx.x] = v;
}

__global__ __launch_bounds__(256) void k_scan2(const int* __restrict__ bsum,
        int* __restrict__ boff, int* __restrict__ off, int nb, int N) {
    __shared__ int sh[256];
    int t = threadIdx.x;
    int d = (t < nb) ? bsum[t] : 0;
    sh[t] = d;
    __syncthreads();
    int v = d;
    #pragma unroll
    for (int o = 1; o < 256; o <<= 1) {
        int u = (t >= o) ? sh[t - o] : 0;
        __syncthreads();
        v += u;
        sh[t] = v;
        __syncthreads();
    }
    if (t < nb) boff[t] = v - d;
    if (t == 255) off[N] = v;
}

__global__ __launch_bounds__(256) void k_scan3(const int* __restrict__ locscan,
        const int* __restrict__ boff, int* __restrict__ off, int* __restrict__ cur, int N) {
    int i = blockIdx.x * 256 + threadIdx.x;
    if (i < N) {
        int v = locscan[i] + boff[blockIdx.x];
        off[i] = v;
        cur[i] = v;
    }
}

// scatter edges into CSR; payload = (src, norm) packed as int2 (one 8B store)
__global__ void k_scatter(const int* __restrict__ src, const int* __restrict__ dst,
        int* __restrict__ cur, int2* __restrict__ sedge,
        const float* __restrict__ dinv, int E) {
    int e = blockIdx.x * blockDim.x + threadIdx.x;
    if (e < E) {
        int s = src[e], d = dst[e];
        int pos = atomicAdd(&cur[d], 1);
        sedge[pos] = make_int2(s, __float_as_int(dinv[s] * dinv[d]));
    }
}

// O_half = X @ W   (X: nrows x 128 f32, W: 128 x 128 row-major f32, out fp16)
// Wave holds W[k][c] for its 64 channels in VGPRs. X row address is wave-uniform
// (readfirstlane) -> scalar loads (s_load) on the SMEM pipe, pure fma on VALU.
__global__ __launch_bounds__(256) void k_gemm_h(const float* __restrict__ X,
        const float* __restrict__ W, __half* __restrict__ Oh, int nrows) {
    int wave = threadIdx.x >> 6, lane = threadIdx.x & 63;
    int c = (wave & 1) * 64 + lane;      // my output channel
    float w[128];
    #pragma unroll
    for (int k = 0; k < 128; ++k) w[k] = W[k * 128 + c];

    int stream0 = blockIdx.x * 2 + (wave >> 1);
    int sstride = gridDim.x * 2;
    for (int row = stream0; row < nrows; row += sstride) {
        int r = rfl(row);
        const float* __restrict__ xr = X + (size_t)r * 128;
        float acc = 0.f;
        #pragma unroll
        for (int kc = 0; kc < 128; kc += 32) {
            float xs[32];
            #pragma unroll
            for (int t = 0; t < 32; ++t) xs[t] = xr[kc + t];
            #pragma unroll
            for (int t = 0; t < 32; ++t) acc = fmaf(xs[t], w[kc + t], acc);
        }
        Oh[(size_t)r * 128 + c] = __float2half(acc);
    }
}

// GCN aggregate, fp16 gathers:
// O[i] = relu( sum_e Hh[src_e]*nrm_e + Hh[i]*dinv[i]^2 + bias ),  f32 accumulate
__global__ __launch_bounds__(256) void k_agg(const __half* __restrict__ Hh,
        const float* __restrict__ dinv, const int* __restrict__ off,
        const int2* __restrict__ se, const float* __restrict__ bias,
        float* __restrict__ O, int N) {
    int lane = threadIdx.x & 63;
    int w = (blockIdx.x * blockDim.x + threadIdx.x) >> 6;
    int nw = (gridDim.x * blockDim.x) >> 6;
    float2 bv = *(const float2*)&bias[2 * lane];
    for (int i = w; i < N; i += nw) {
        int iu = rfl(i);
        float di = dinv[iu];
        int j0 = rfl(off[iu]);
        int j1 = rfl(off[iu + 1]);
        float2 hv = __half22float2(((const __half2*)(Hh + (size_t)iu * 128))[lane]);
        float sl = di * di;
        float a0 = hv.x * sl, a1 = hv.y * sl;
        int j = j0;
        for (; j + 8 <= j1; j += 8) {
            int2 e0 = se[j],     e1 = se[j + 1], e2 = se[j + 2], e3 = se[j + 3];
            int2 e4 = se[j + 4], e5 = se[j + 5], e6 = se[j + 6], e7 = se[j + 7];
            int s0 = rfl(e0.x), s1 = rfl(e1.x), s2 = rfl(e2.x), s3 = rfl(e3.x);
            int s4 = rfl(e4.x), s5 = rfl(e5.x), s6 = rfl(e6.x), s7 = rfl(e7.x);
            __half2 g0 = ((const __half2*)(Hh + (size_t)s0 * 128))[lane];
            __half2 g1 = ((const __half2*)(Hh + (size_t)s1 * 128))[lane];
            __half2 g2 = ((const __half2*)(Hh + (size_t)s2 * 128))[lane];
            __half2 g3 = ((const __half2*)(Hh + (size_t)s3 * 128))[lane];
            __half2 g4 = ((const __half2*)(Hh + (size_t)s4 * 128))[lane];
            __half2 g5 = ((const __half2*)(Hh + (size_t)s5 * 128))[lane];
            __half2 g6 = ((const __half2*)(Hh + (size_t)s6 * 128))[lane];
            __half2 g7 = ((const __half2*)(Hh + (size_t)s7 * 128))[lane];
            float m0 = __int_as_float(e0.y), m1 = __int_as_float(e1.y);
            float m2 = __int_as_float(e2.y), m3 = __int_as_float(e3.y);
            float m4 = __int_as_float(e4.y), m5 = __int_as_float(e5.y);
            float m6 = __int_as_float(e6.y), m7 = __int_as_float(e7.y);
            float2 h;
            h = __half22float2(g0); a0 = fmaf(h.x, m0, a0); a1 = fmaf(h.y, m0, a1);
            h = __half22float2(g1); a0 = fmaf(h.x, m1, a0); a1 = fmaf(h.y, m1, a1);
            h = __half22float2(g2); a0 = fmaf(h.x, m2, a0); a1 = fmaf(h.y, m2, a1);
            h = __half22float2(g3); a0 = fmaf(h.x, m3, a0); a1 = fmaf(h.y, m3, a1);
            h = __half22float2(g4); a0 = fmaf(h.x, m4, a0); a1 = fmaf(h.y, m4, a1);
            h = __half22float2(g5); a0 = fmaf(h.x, m5, a0); a1 = fmaf(h.y, m5, a1);
            h = __half22float2(g6); a0 = fmaf(h.x, m6, a0); a1 = fmaf(h.y, m6, a1);
            h = __half22float2(g7); a0 = fmaf(h.x, m7, a0); a1 = fmaf(h.y, m7, a1);
        }
        for (; j + 4 <= j1; j += 4) {
            int2 e0 = se[j], e1 = se[j + 1], e2 = se[j + 2], e3 = se[j + 3];
            int s0 = rfl(e0.x), s1 = rfl(e1.x), s2 = rfl(e2.x), s3 = rfl(e3.x);
            __half2 g0 = ((const __half2*)(Hh + (size_t)s0 * 128))[lane];
            __half2 g1 = ((const __half2*)(Hh + (size_t)s1 * 128))[lane];
            __half2 g2 = ((const __half2*)(Hh + (size_t)s2 * 128))[lane];
            __half2 g3 = ((const __half2*)(Hh + (size_t)s3 * 128))[lane];
            float m0 = __int_as_float(e0.y), m1 = __int_as_float(e1.y);
            float m2 = __int_as_float(e2.y), m3 = __int_as_float(e3.y);
            float2 h;
            h = __half22float2(g0); a0 = fmaf(h.x, m0, a0); a1 = fmaf(h.y, m0, a1);
            h = __half22float2(g1); a0 = fmaf(h.x, m1, a0); a1 = fmaf(h.y, m1, a1);
            h = __half22float2(g2); a0 = fmaf(h.x, m2, a0); a1 = fmaf(h.y, m2, a1);
            h = __half22float2(g3); a0 = fmaf(h.x, m3, a0); a1 = fmaf(h.y, m3, a1);
        }
        for (; j < j1; ++j) {
            int2 e0 = se[j];
            int s0 = rfl(e0.x);
            __half2 g0 = ((const __half2*)(Hh + (size_t)s0 * 128))[lane];
            float m0 = __int_as_float(e0.y);
            float2 h = __half22float2(g0);
            a0 = fmaf(h.x, m0, a0); a1 = fmaf(h.y, m0, a1);
        }
        a0 += bv.x; a1 += bv.y;
        a0 = fmaxf(a0, 0.f); a1 = fmaxf(a1, 0.f);
        *(float2*)&O[(size_t)iu * 128 + 2 * lane] = make_float2(a0, a1);
    }
}

// parallel partial mean-pool: sorted batch -> register accumulate, flush on graph change
__global__ __launch_bounds__(256) void k_pool_part(const float* __restrict__ X,
        const int* __restrict__ batch, float* __restrict__ pooled, int N) {
    int c = threadIdx.x & 127, sub = threadIdx.x >> 7;
    int chunk = (N + gridDim.x - 1) / gridDim.x;
    int b = blockIdx.x * chunk, e = min(b + chunk, N);
    float acc = 0.f;
    int cg = -1;
    for (int n = b + sub; n < e; n += 2) {
        int g = batch[n];
        if (g != cg) {
            if (cg >= 0) atomicAdd(&pooled[cg * 128 + c], acc);
            acc = 0.f;
            cg = g;
        }
        acc += X[(size_t)n * 128 + c];
    }
    if (cg >= 0) atomicAdd(&pooled[cg * 128 + c], acc);
}

// final: divide by per-graph count and apply Wlin
__global__ void k_final(const float* __restrict__ P, const int* __restrict__ batch,
        const float* __restrict__ Wl, const float* __restrict__ bl,
        float* __restrict__ out, int G, int CO, int N) {
    int t = blockIdx.x * blockDim.x + threadIdx.x;
    if (t >= G * CO) return;
    int g = t / CO, o = t % CO;
    int cnt = lowerb(batch, N, g + 1) - lowerb(batch, N, g);
    float inv = cnt > 0 ? 1.0f / (float)cnt : 0.0f;
    float acc = bl[o];
    for (int k = 0; k < 128; ++k) acc += P[g * 128 + k] * inv * Wl[k * CO + o];
    out[t] = acc;
}

// ---------------- launcher ----------------
extern "C" void kernel_launch(void* const* d_in, const int* in_sizes, int n_in,
                              void* d_out, int out_size, void* d_ws, size_t ws_size,
                              hipStream_t stream) {
    const float* x     = (const float*)d_in[0];
    const int*   ei    = (const int*)d_in[1];
    const int*   batch = (const int*)d_in[2];
    const float* W1e   = (const float*)d_in[5];
    const float* b1e   = (const float*)d_in[6];
    const float* W2e   = (const float*)d_in[9];
    const float* b2e   = (const float*)d_in[10];
    const float* Wlin  = (const float*)d_in[11];
    const float* blin  = (const float*)d_in[12];
    float* out = (float*)d_out;

    int N  = in_sizes[0] / 128;
    int E  = in_sizes[1] / 2;
    int CO = in_sizes[12];          // 10
    int G  = out_size / CO;         // 64

    const int* src = ei;
    const int* dst = ei + E;

    int* deg  = (int*)d_ws;                        // N
    int* off  = deg + N;                           // N+1 (pad 4)
    int* cur  = off + (N + 4);                     // N
    int2* sedge = (int2*)(cur + N);                // E int2
    float* dinv   = (float*)(sedge + E);           // N
    __half* hh    = (__half*)(dinv + N);           // N*128 fp16 (N*64 words)
    float* xbuf   = (float*)(hh + (size_t)N * 128);// N*128 f32
    float* pooled = xbuf + (size_t)N * 128;        // G*128
    int* locscan  = (int*)(pooled + (size_t)G * 128);  // N
    int* bsum     = locscan + N;                   // 256
    int* boff     = bsum + 256;                    // 256

    int nb = (N + 255) / 256;

    k_zero_i32<<<(N + 255) / 256, 256, 0, stream>>>(deg, N);
    k_zero_i32<<<(G * 128 + 255) / 256, 256, 0, stream>>>((int*)pooled, G * 128);
    k_hist<<<(E + 255) / 256, 256, 0, stream>>>(dst, deg, E);
    k_scan1<<<nb, 256, 0, stream>>>(deg, locscan, bsum, dinv, N);
    k_scan2<<<1, 256, 0, stream>>>(bsum, boff, off, nb, N);
    k_scan3<<<nb, 256, 0, stream>>>(locscan, boff, off, cur, N);
    k_scatter<<<(E + 255) / 256, 256, 0, stream>>>(src, dst, cur, sedge, dinv, E);

    k_gemm_h<<<1024, 256, 0, stream>>>(x, W1e, hh, N);
    k_agg<<<2048, 256, 0, stream>>>(hh, dinv, off, sedge, b1e, xbuf, N);
    k_gemm_h<<<1024, 256, 0, stream>>>(xbuf, W2e, hh, N);
    k_agg<<<2048, 256, 0, stream>>>(hh, dinv, off, sedge, b2e, xbuf, N);

    k_pool_part<<<512, 256, 0, stream>>>(xbuf, batch, pooled, N);
    k_final<<<3, 256, 0, stream>>>(pooled, batch, Wlin, blin, out, G, CO, N);
}

// Round 5
// 259.468 us; speedup vs baseline: 2.1630x; 1.3360x over previous
//
#include <hip/hip_runtime.h>
#include <hip/hip_fp16.h>

typedef _Float16 half8 __attribute__((ext_vector_type(8)));
typedef _Float16 half4v __attribute__((ext_vector_type(4)));
typedef float f32x4 __attribute__((ext_vector_type(4)));

// ---------------- helpers ----------------
__device__ __forceinline__ int rfl(int v) { return __builtin_amdgcn_readfirstlane(v); }

__device__ __forceinline__ int lowerb(const int* a, int n, int v) {
    int lo = 0, hi = n;
    while (lo < hi) { int m = (lo + hi) >> 1; if (a[m] < v) lo = m + 1; else hi = m; }
    return lo;
}

// ---------------- setup kernels ----------------
__global__ void k_zero_i32(int* __restrict__ p, int n) {
    int i = blockIdx.x * blockDim.x + threadIdx.x;
    if (i < n) p[i] = 0;
}

__global__ void k_hist(const int* __restrict__ dst, int* __restrict__ deg, int E) {
    int e = blockIdx.x * blockDim.x + threadIdx.x;
    if (e < E) atomicAdd(&deg[dst[e]], 1);
}

__global__ __launch_bounds__(256) void k_scan1(const int* __restrict__ deg,
        int* __restrict__ locscan, int* __restrict__ bsum, float* __restrict__ dinv, int N) {
    __shared__ int sh[256];
    int t = threadIdx.x;
    int i = blockIdx.x * 256 + t;
    int d = (i < N) ? deg[i] : 0;
    sh[t] = d;
    __syncthreads();
    int v = d;
    #pragma unroll
    for (int o = 1; o < 256; o <<= 1) {
        int u = (t >= o) ? sh[t - o] : 0;
        __syncthreads();
        v += u;
        sh[t] = v;
        __syncthreads();
    }
    if (i < N) {
        locscan[i] = v - d;
        dinv[i] = rsqrtf((float)d + 1.0f);
    }
    if (t == 255) bsum[blockIdx.x] = v;
}

__global__ __launch_bounds__(256) void k_scan2(const int* __restrict__ bsum,
        int* __restrict__ boff, int* __restrict__ off, int nb, int N) {
    __shared__ int sh[256];
    int t = threadIdx.x;
    int d = (t < nb) ? bsum[t] : 0;
    sh[t] = d;
    __syncthreads();
    int v = d;
    #pragma unroll
    for (int o = 1; o < 256; o <<= 1) {
        int u = (t >= o) ? sh[t - o] : 0;
        __syncthreads();
        v += u;
        sh[t] = v;
        __syncthreads();
    }
    if (t < nb) boff[t] = v - d;
    if (t == 255) off[N] = v;
}

__global__ __launch_bounds__(256) void k_scan3(const int* __restrict__ locscan,
        const int* __restrict__ boff, int* __restrict__ off, int* __restrict__ cur, int N) {
    int i = blockIdx.x * 256 + threadIdx.x;
    if (i < N) {
        int v = locscan[i] + boff[blockIdx.x];
        off[i] = v;
        cur[i] = v;
    }
}

__global__ void k_scatter(const int* __restrict__ src, const int* __restrict__ dst,
        int* __restrict__ cur, int2* __restrict__ sedge,
        const float* __restrict__ dinv, int E) {
    int e = blockIdx.x * blockDim.x + threadIdx.x;
    if (e < E) {
        int s = src[e], d = dst[e];
        int pos = atomicAdd(&cur[d], 1);
        sedge[pos] = make_int2(s, __float_as_int(dinv[s] * dinv[d]));
    }
}

// x (f32) -> xh (fp16), vectorized
__global__ void k_x2h(const float* __restrict__ x, _Float16* __restrict__ xh, int n4) {
    int i = blockIdx.x * blockDim.x + threadIdx.x;
    int stride = gridDim.x * blockDim.x;
    for (; i < n4; i += stride) {
        float4 v = ((const float4*)x)[i];
        half4v h = { (_Float16)v.x, (_Float16)v.y, (_Float16)v.z, (_Float16)v.w };
        ((half4v*)xh)[i] = h;
    }
}

// pack W (128x128 f32 row-major, W[k][n]) into fp16 MFMA B-fragment order:
// wfrag[((nt*4+t)*64 + l)*8 + j] = W[(t*32 + (l>>4)*8 + j)][nt*16 + (l&15)]
__global__ __launch_bounds__(256) void k_prep_w(const float* __restrict__ W,
        _Float16* __restrict__ wfrag) {
    for (int idx = threadIdx.x; idx < 16384; idx += 256) {
        int j  = idx & 7;
        int l  = (idx >> 3) & 63;
        int t  = (idx >> 9) & 3;
        int nt = idx >> 11;
        int k  = t * 32 + (l >> 4) * 8 + j;
        int n  = nt * 16 + (l & 15);
        wfrag[idx] = (_Float16)W[k * 128 + n];
    }
}

// MFMA GEMM: Hh[r][c] = sum_k Xh[r][k] * W[k][c]   (fp16 in, f32 acc, fp16 out)
// wave-task = 16-row strip x 64-col half. B-frags (16 x half8 = 64 VGPR) loop-invariant.
__global__ __launch_bounds__(256, 2) void k_gemm_mfma(const _Float16* __restrict__ Xh,
        const _Float16* __restrict__ wfrag, _Float16* __restrict__ Hh, int nrows) {
    int w = threadIdx.x >> 6, l = threadIdx.x & 63;
    int gw = blockIdx.x * 4 + w;
    int ch = gw & 1;              // column half (0: cols 0..63, 1: 64..127)
    int strip0 = gw >> 1;
    int sstride = gridDim.x * 2;

    half8 b[4][4];                // [q = col-tile within half][t = k-frag]
    #pragma unroll
    for (int q = 0; q < 4; ++q)
        #pragma unroll
        for (int t = 0; t < 4; ++t)
            b[q][t] = *(const half8*)&wfrag[(((ch * 4 + q) * 4 + t) * 64 + l) * 8];

    int row_in = l & 15;
    int kb = l >> 4;
    int nstrips = (nrows + 15) >> 4;
    for (int s = strip0; s < nstrips; s += sstride) {
        int m0 = s << 4;
        int rl = m0 + row_in; if (rl > nrows - 1) rl = nrows - 1;
        const _Float16* xr = Xh + (size_t)rl * 128 + kb * 8;
        half8 a[4];
        #pragma unroll
        for (int t = 0; t < 4; ++t) a[t] = *(const half8*)(xr + t * 32);

        f32x4 acc[4];
        #pragma unroll
        for (int q = 0; q < 4; ++q) acc[q] = (f32x4){0.f, 0.f, 0.f, 0.f};
        #pragma unroll
        for (int t = 0; t < 4; ++t)
            #pragma unroll
            for (int q = 0; q < 4; ++q)
                acc[q] = __builtin_amdgcn_mfma_f32_16x16x32_f16(a[t], b[q][t], acc[q], 0, 0, 0);

        int orow = m0 + (l >> 4) * 4;
        int ocol = ch * 64 + (l & 15);
        _Float16* op = Hh + (size_t)orow * 128 + ocol;
        #pragma unroll
        for (int r = 0; r < 4; ++r) {
            if (orow + r < nrows) {
                #pragma unroll
                for (int q = 0; q < 4; ++q)
                    op[(size_t)r * 128 + q * 16] = (_Float16)acc[q][r];
            }
        }
    }
}

// GCN aggregate, fp16 gathers, f32 accumulate.
// OUTH=1: write fp16 (feeds next GEMM); OUTH=0: write f32 (feeds pool).
template <int OUTH>
__global__ __launch_bounds__(256) void k_agg(const __half* __restrict__ Hh,
        const float* __restrict__ dinv, const int* __restrict__ off,
        const int2* __restrict__ se, const float* __restrict__ bias,
        void* __restrict__ Ov, int N) {
    int lane = threadIdx.x & 63;
    int w = (blockIdx.x * blockDim.x + threadIdx.x) >> 6;
    int nw = (gridDim.x * blockDim.x) >> 6;
    float2 bv = *(const float2*)&bias[2 * lane];
    for (int i = w; i < N; i += nw) {
        int iu = rfl(i);
        float di = dinv[iu];
        int j0 = rfl(off[iu]);
        int j1 = rfl(off[iu + 1]);
        float2 hv = __half22float2(((const __half2*)(Hh + (size_t)iu * 128))[lane]);
        float sl = di * di;
        float a0 = hv.x * sl, a1 = hv.y * sl;
        int j = j0;
        for (; j + 8 <= j1; j += 8) {
            int2 e0 = se[j],     e1 = se[j + 1], e2 = se[j + 2], e3 = se[j + 3];
            int2 e4 = se[j + 4], e5 = se[j + 5], e6 = se[j + 6], e7 = se[j + 7];
            int s0 = rfl(e0.x), s1 = rfl(e1.x), s2 = rfl(e2.x), s3 = rfl(e3.x);
            int s4 = rfl(e4.x), s5 = rfl(e5.x), s6 = rfl(e6.x), s7 = rfl(e7.x);
            __half2 g0 = ((const __half2*)(Hh + (size_t)s0 * 128))[lane];
            __half2 g1 = ((const __half2*)(Hh + (size_t)s1 * 128))[lane];
            __half2 g2 = ((const __half2*)(Hh + (size_t)s2 * 128))[lane];
            __half2 g3 = ((const __half2*)(Hh + (size_t)s3 * 128))[lane];
            __half2 g4 = ((const __half2*)(Hh + (size_t)s4 * 128))[lane];
            __half2 g5 = ((const __half2*)(Hh + (size_t)s5 * 128))[lane];
            __half2 g6 = ((const __half2*)(Hh + (size_t)s6 * 128))[lane];
            __half2 g7 = ((const __half2*)(Hh + (size_t)s7 * 128))[lane];
            float m0 = __int_as_float(e0.y), m1 = __int_as_float(e1.y);
            float m2 = __int_as_float(e2.y), m3 = __int_as_float(e3.y);
            float m4 = __int_as_float(e4.y), m5 = __int_as_float(e5.y);
            float m6 = __int_as_float(e6.y), m7 = __int_as_float(e7.y);
            float2 h;
            h = __half22float2(g0); a0 = fmaf(h.x, m0, a0); a1 = fmaf(h.y, m0, a1);
            h = __half22float2(g1); a0 = fmaf(h.x, m1, a0); a1 = fmaf(h.y, m1, a1);
            h = __half22float2(g2); a0 = fmaf(h.x, m2, a0); a1 = fmaf(h.y, m2, a1);
            h = __half22float2(g3); a0 = fmaf(h.x, m3, a0); a1 = fmaf(h.y, m3, a1);
            h = __half22float2(g4); a0 = fmaf(h.x, m4, a0); a1 = fmaf(h.y, m4, a1);
            h = __half22float2(g5); a0 = fmaf(h.x, m5, a0); a1 = fmaf(h.y, m5, a1);
            h = __half22float2(g6); a0 = fmaf(h.x, m6, a0); a1 = fmaf(h.y, m6, a1);
            h = __half22float2(g7); a0 = fmaf(h.x, m7, a0); a1 = fmaf(h.y, m7, a1);
        }
        for (; j + 4 <= j1; j += 4) {
            int2 e0 = se[j], e1 = se[j + 1], e2 = se[j + 2], e3 = se[j + 3];
            int s0 = rfl(e0.x), s1 = rfl(e1.x), s2 = rfl(e2.x), s3 = rfl(e3.x);
            __half2 g0 = ((const __half2*)(Hh + (size_t)s0 * 128))[lane];
            __half2 g1 = ((const __half2*)(Hh + (size_t)s1 * 128))[lane];
            __half2 g2 = ((const __half2*)(Hh + (size_t)s2 * 128))[lane];
            __half2 g3 = ((const __half2*)(Hh + (size_t)s3 * 128))[lane];
            float m0 = __int_as_float(e0.y), m1 = __int_as_float(e1.y);
            float m2 = __int_as_float(e2.y), m3 = __int_as_float(e3.y);
            float2 h;
            h = __half22float2(g0); a0 = fmaf(h.x, m0, a0); a1 = fmaf(h.y, m0, a1);
            h = __half22float2(g1); a0 = fmaf(h.x, m1, a0); a1 = fmaf(h.y, m1, a1);
            h = __half22float2(g2); a0 = fmaf(h.x, m2, a0); a1 = fmaf(h.y, m2, a1);
            h = __half22float2(g3); a0 = fmaf(h.x, m3, a0); a1 = fmaf(h.y, m3, a1);
        }
        for (; j < j1; ++j) {
            int2 e0 = se[j];
            int s0 = rfl(e0.x);
            __half2 g0 = ((const __half2*)(Hh + (size_t)s0 * 128))[lane];
            float m0 = __int_as_float(e0.y);
            float2 h = __half22float2(g0);
            a0 = fmaf(h.x, m0, a0); a1 = fmaf(h.y, m0, a1);
        }
        a0 += bv.x; a1 += bv.y;
        a0 = fmaxf(a0, 0.f); a1 = fmaxf(a1, 0.f);
        if (OUTH) {
            ((__half2*)((__half*)Ov + (size_t)iu * 128))[lane] = __floats2half2_rn(a0, a1);
        } else {
            *(float2*)((float*)Ov + (size_t)iu * 128 + 2 * lane) = make_float2(a0, a1);
        }
    }
}

// parallel partial mean-pool: sorted batch -> register accumulate, flush on graph change
__global__ __launch_bounds__(256) void k_pool_part(const float* __restrict__ X,
        const int* __restrict__ batch, float* __restrict__ pooled, int N) {
    int c = threadIdx.x & 127, sub = threadIdx.x >> 7;
    int chunk = (N + gridDim.x - 1) / gridDim.x;
    int b = blockIdx.x * chunk, e = min(b + chunk, N);
    float acc = 0.f;
    int cg = -1;
    for (int n = b + sub; n < e; n += 2) {
        int g = batch[n];
        if (g != cg) {
            if (cg >= 0) atomicAdd(&pooled[cg * 128 + c], acc);
            acc = 0.f;
            cg = g;
        }
        acc += X[(size_t)n * 128 + c];
    }
    if (cg >= 0) atomicAdd(&pooled[cg * 128 + c], acc);
}

__global__ void k_final(const float* __restrict__ P, const int* __restrict__ batch,
        const float* __restrict__ Wl, const float* __restrict__ bl,
        float* __restrict__ out, int G, int CO, int N) {
    int t = blockIdx.x * blockDim.x + threadIdx.x;
    if (t >= G * CO) return;
    int g = t / CO, o = t % CO;
    int cnt = lowerb(batch, N, g + 1) - lowerb(batch, N, g);
    float inv = cnt > 0 ? 1.0f / (float)cnt : 0.0f;
    float acc = bl[o];
    for (int k = 0; k < 128; ++k) acc += P[g * 128 + k] * inv * Wl[k * CO + o];
    out[t] = acc;
}

// ---------------- launcher ----------------
extern "C" void kernel_launch(void* const* d_in, const int* in_sizes, int n_in,
                              void* d_out, int out_size, void* d_ws, size_t ws_size,
                              hipStream_t stream) {
    const float* x     = (const float*)d_in[0];
    const int*   ei    = (const int*)d_in[1];
    const int*   batch = (const int*)d_in[2];
    const float* W1e   = (const float*)d_in[5];
    const float* b1e   = (const float*)d_in[6];
    const float* W2e   = (const float*)d_in[9];
    const float* b2e   = (const float*)d_in[10];
    const float* Wlin  = (const float*)d_in[11];
    const float* blin  = (const float*)d_in[12];
    float* out = (float*)d_out;

    int N  = in_sizes[0] / 128;
    int E  = in_sizes[1] / 2;
    int CO = in_sizes[12];          // 10
    int G  = out_size / CO;         // 64

    const int* src = ei;
    const int* dst = ei + E;

    int* deg  = (int*)d_ws;                          // N
    int* off  = deg + N;                             // N+1 (pad 4)
    int* cur  = off + (N + 4);                       // N
    int2* sedge = (int2*)(cur + N);                  // E int2
    float* dinv   = (float*)(sedge + E);             // N
    _Float16* hh  = (_Float16*)(dinv + N);           // N*128 fp16
    _Float16* xh  = hh + (size_t)N * 128;            // N*128 fp16 (X fp16, reused as x1h)
    float* xbuf   = (float*)(xh + (size_t)N * 128);  // N*128 f32
    float* pooled = xbuf + (size_t)N * 128;          // G*128
    _Float16* wfrag = (_Float16*)(pooled + (size_t)G * 128);  // 16384 halves
    int* locscan  = (int*)(wfrag + 16384);           // N
    int* bsum     = locscan + N;                     // 256
    int* boff     = bsum + 256;                      // 256

    int nb = (N + 255) / 256;

    k_zero_i32<<<(N + 255) / 256, 256, 0, stream>>>(deg, N);
    k_zero_i32<<<(G * 128 + 255) / 256, 256, 0, stream>>>((int*)pooled, G * 128);
    k_hist<<<(E + 255) / 256, 256, 0, stream>>>(dst, deg, E);
    k_scan1<<<nb, 256, 0, stream>>>(deg, locscan, bsum, dinv, N);
    k_scan2<<<1, 256, 0, stream>>>(bsum, boff, off, nb, N);
    k_scan3<<<nb, 256, 0, stream>>>(locscan, boff, off, cur, N);
    k_scatter<<<(E + 255) / 256, 256, 0, stream>>>(src, dst, cur, sedge, dinv, E);

    k_x2h<<<2048, 256, 0, stream>>>(x, xh, N * 32);

    int nstrips = (N + 15) / 16;
    int gemm_blocks = (nstrips * 2 + 3) / 4;

    // layer 1
    k_prep_w<<<1, 256, 0, stream>>>(W1e, wfrag);
    k_gemm_mfma<<<gemm_blocks, 256, 0, stream>>>(xh, wfrag, hh, N);
    k_agg<1><<<2048, 256, 0, stream>>>((const __half*)hh, dinv, off, sedge, b1e, (void*)xh, N);
    // layer 2
    k_prep_w<<<1, 256, 0, stream>>>(W2e, wfrag);
    k_gemm_mfma<<<gemm_blocks, 256, 0, stream>>>(xh, wfrag, hh, N);
    k_agg<0><<<2048, 256, 0, stream>>>((const __half*)hh, dinv, off, sedge, b2e, (void*)xbuf, N);

    k_pool_part<<<512, 256, 0, stream>>>(xbuf, batch, pooled, N);
    k_final<<<3, 256, 0, stream>>>(pooled, batch, Wlin, blin, out, G, CO, N);
}

// Round 6
// 254.934 us; speedup vs baseline: 2.2015x; 1.0178x over previous
//
#include <hip/hip_runtime.h>
#include <hip/hip_fp16.h>

typedef _Float16 half8 __attribute__((ext_vector_type(8)));
typedef _Float16 half4v __attribute__((ext_vector_type(4)));
typedef float f32x4 __attribute__((ext_vector_type(4)));

#define NXCD 8

// ---------------- helpers ----------------
__device__ __forceinline__ int rfl(int v) { return __builtin_amdgcn_readfirstlane(v); }

__device__ __forceinline__ int lowerb(const int* a, int n, int v) {
    int lo = 0, hi = n;
    while (lo < hi) { int m = (lo + hi) >> 1; if (a[m] < v) lo = m + 1; else hi = m; }
    return lo;
}

// ---------------- setup kernels ----------------
__global__ void k_zero_i32(int* __restrict__ p, int n) {
    int i = blockIdx.x * blockDim.x + threadIdx.x;
    if (i < n) p[i] = 0;
}

// XCD-partitioned histogram: block b reads chunk b/8, histograms only dst in
// XCD-range (b&7). Atomics stay in one XCD's L2 slice (no line ping-pong).
__global__ __launch_bounds__(256) void k_hist_x(const int* __restrict__ dst,
        int* __restrict__ deg, int E, int N, int csz) {
    int xcd = blockIdx.x & (NXCD - 1);
    int chunk = blockIdx.x >> 3;
    int lo = (int)(((long long)xcd * N) >> 3);
    int hi = (int)(((long long)(xcd + 1) * N) >> 3);
    int e0 = chunk * csz, e1 = min(e0 + csz, E);
    for (int e = e0 + threadIdx.x; e < e1; e += 256) {
        int d = dst[e];
        if (d >= lo && d < hi) atomicAdd(&deg[d], 1);
    }
}

__global__ __launch_bounds__(256) void k_scan1(const int* __restrict__ deg,
        int* __restrict__ locscan, int* __restrict__ bsum, float* __restrict__ dinv, int N) {
    __shared__ int sh[256];
    int t = threadIdx.x;
    int i = blockIdx.x * 256 + t;
    int d = (i < N) ? deg[i] : 0;
    sh[t] = d;
    __syncthreads();
    int v = d;
    #pragma unroll
    for (int o = 1; o < 256; o <<= 1) {
        int u = (t >= o) ? sh[t - o] : 0;
        __syncthreads();
        v += u;
        sh[t] = v;
        __syncthreads();
    }
    if (i < N) {
        locscan[i] = v - d;
        dinv[i] = rsqrtf((float)d + 1.0f);
    }
    if (t == 255) bsum[blockIdx.x] = v;
}

__global__ __launch_bounds__(256) void k_scan2(const int* __restrict__ bsum,
        int* __restrict__ boff, int* __restrict__ off, int nb, int N) {
    __shared__ int sh[256];
    int t = threadIdx.x;
    int d = (t < nb) ? bsum[t] : 0;
    sh[t] = d;
    __syncthreads();
    int v = d;
    #pragma unroll
    for (int o = 1; o < 256; o <<= 1) {
        int u = (t >= o) ? sh[t - o] : 0;
        __syncthreads();
        v += u;
        sh[t] = v;
        __syncthreads();
    }
    if (t < nb) boff[t] = v - d;
    if (t == 255) off[N] = v;
}

__global__ __launch_bounds__(256) void k_scan3(const int* __restrict__ locscan,
        const int* __restrict__ boff, int* __restrict__ off, int* __restrict__ cur, int N) {
    int i = blockIdx.x * 256 + threadIdx.x;
    if (i < N) {
        int v = locscan[i] + boff[blockIdx.x];
        off[i] = v;
        cur[i] = v;
    }
}

// XCD-partitioned CSR scatter: same chunk/range scheme as k_hist_x.
// All atomicAdd(cur) and sedge writes land in the local XCD's L2 slice.
__global__ __launch_bounds__(256) void k_scatter_x(const int* __restrict__ src,
        const int* __restrict__ dst, int* __restrict__ cur, int2* __restrict__ sedge,
        const float* __restrict__ dinv, int E, int N, int csz) {
    int xcd = blockIdx.x & (NXCD - 1);
    int chunk = blockIdx.x >> 3;
    int lo = (int)(((long long)xcd * N) >> 3);
    int hi = (int)(((long long)(xcd + 1) * N) >> 3);
    int e0 = chunk * csz, e1 = min(e0 + csz, E);
    for (int e = e0 + threadIdx.x; e < e1; e += 256) {
        int d = dst[e];
        if (d >= lo && d < hi) {
            int s = src[e];
            int pos = atomicAdd(&cur[d], 1);
            sedge[pos] = make_int2(s, __float_as_int(dinv[s] * dinv[d]));
        }
    }
}

// x (f32) -> xh (fp16), vectorized
__global__ void k_x2h(const float* __restrict__ x, _Float16* __restrict__ xh, int n4) {
    int i = blockIdx.x * blockDim.x + threadIdx.x;
    int stride = gridDim.x * blockDim.x;
    for (; i < n4; i += stride) {
        float4 v = ((const float4*)x)[i];
        half4v h = { (_Float16)v.x, (_Float16)v.y, (_Float16)v.z, (_Float16)v.w };
        ((half4v*)xh)[i] = h;
    }
}

// pack W (128x128 f32 row-major, W[k][n]) into fp16 MFMA B-fragment order
__global__ __launch_bounds__(256) void k_prep_w(const float* __restrict__ W,
        _Float16* __restrict__ wfrag) {
    for (int idx = threadIdx.x; idx < 16384; idx += 256) {
        int j  = idx & 7;
        int l  = (idx >> 3) & 63;
        int t  = (idx >> 9) & 3;
        int nt = idx >> 11;
        int k  = t * 32 + (l >> 4) * 8 + j;
        int n  = nt * 16 + (l & 15);
        wfrag[idx] = (_Float16)W[k * 128 + n];
    }
}

// MFMA GEMM: Hh[r][c] = sum_k Xh[r][k] * W[k][c]   (fp16 in, f32 acc, fp16 out)
__global__ __launch_bounds__(256, 2) void k_gemm_mfma(const _Float16* __restrict__ Xh,
        const _Float16* __restrict__ wfrag, _Float16* __restrict__ Hh, int nrows) {
    int w = threadIdx.x >> 6, l = threadIdx.x & 63;
    int gw = blockIdx.x * 4 + w;
    int ch = gw & 1;
    int strip0 = gw >> 1;
    int sstride = gridDim.x * 2;

    half8 b[4][4];
    #pragma unroll
    for (int q = 0; q < 4; ++q)
        #pragma unroll
        for (int t = 0; t < 4; ++t)
            b[q][t] = *(const half8*)&wfrag[(((ch * 4 + q) * 4 + t) * 64 + l) * 8];

    int row_in = l & 15;
    int kb = l >> 4;
    int nstrips = (nrows + 15) >> 4;
    for (int s = strip0; s < nstrips; s += sstride) {
        int m0 = s << 4;
        int rl = m0 + row_in; if (rl > nrows - 1) rl = nrows - 1;
        const _Float16* xr = Xh + (size_t)rl * 128 + kb * 8;
        half8 a[4];
        #pragma unroll
        for (int t = 0; t < 4; ++t) a[t] = *(const half8*)(xr + t * 32);

        f32x4 acc[4];
        #pragma unroll
        for (int q = 0; q < 4; ++q) acc[q] = (f32x4){0.f, 0.f, 0.f, 0.f};
        #pragma unroll
        for (int t = 0; t < 4; ++t)
            #pragma unroll
            for (int q = 0; q < 4; ++q)
                acc[q] = __builtin_amdgcn_mfma_f32_16x16x32_f16(a[t], b[q][t], acc[q], 0, 0, 0);

        int orow = m0 + (l >> 4) * 4;
        int ocol = ch * 64 + (l & 15);
        _Float16* op = Hh + (size_t)orow * 128 + ocol;
        #pragma unroll
        for (int r = 0; r < 4; ++r) {
            if (orow + r < nrows) {
                #pragma unroll
                for (int q = 0; q < 4; ++q)
                    op[(size_t)r * 128 + q * 16] = (_Float16)acc[q][r];
            }
        }
    }
}

// GCN aggregate, fp16 gathers, f32 accumulate, XCD-partitioned node ranges
// (each XCD consumes the sedge slice its own L2 wrote in k_scatter_x).
template <int OUTH>
__global__ __launch_bounds__(256) void k_agg(const __half* __restrict__ Hh,
        const float* __restrict__ dinv, const int* __restrict__ off,
        const int2* __restrict__ se, const float* __restrict__ bias,
        void* __restrict__ Ov, int N) {
    int lane = threadIdx.x & 63;
    int xcd = blockIdx.x & (NXCD - 1);
    int lw  = (blockIdx.x >> 3) * 4 + (threadIdx.x >> 6);  // local wave within xcd
    int nlw = (gridDim.x >> 3) * 4;
    int lo = (int)(((long long)xcd * N) >> 3);
    int hi = (int)(((long long)(xcd + 1) * N) >> 3);
    float2 bv = *(const float2*)&bias[2 * lane];
    for (int i = lo + lw; i < hi; i += nlw) {
        int iu = rfl(i);
        float di = dinv[iu];
        int j0 = rfl(off[iu]);
        int j1 = rfl(off[iu + 1]);
        float2 hv = __half22float2(((const __half2*)(Hh + (size_t)iu * 128))[lane]);
        float sl = di * di;
        float a0 = hv.x * sl, a1 = hv.y * sl;
        int j = j0;
        for (; j + 8 <= j1; j += 8) {
            int2 e0 = se[j],     e1 = se[j + 1], e2 = se[j + 2], e3 = se[j + 3];
            int2 e4 = se[j + 4], e5 = se[j + 5], e6 = se[j + 6], e7 = se[j + 7];
            int s0 = rfl(e0.x), s1 = rfl(e1.x), s2 = rfl(e2.x), s3 = rfl(e3.x);
            int s4 = rfl(e4.x), s5 = rfl(e5.x), s6 = rfl(e6.x), s7 = rfl(e7.x);
            __half2 g0 = ((const __half2*)(Hh + (size_t)s0 * 128))[lane];
            __half2 g1 = ((const __half2*)(Hh + (size_t)s1 * 128))[lane];
            __half2 g2 = ((const __half2*)(Hh + (size_t)s2 * 128))[lane];
            __half2 g3 = ((const __half2*)(Hh + (size_t)s3 * 128))[lane];
            __half2 g4 = ((const __half2*)(Hh + (size_t)s4 * 128))[lane];
            __half2 g5 = ((const __half2*)(Hh + (size_t)s5 * 128))[lane];
            __half2 g6 = ((const __half2*)(Hh + (size_t)s6 * 128))[lane];
            __half2 g7 = ((const __half2*)(Hh + (size_t)s7 * 128))[lane];
            float m0 = __int_as_float(e0.y), m1 = __int_as_float(e1.y);
            float m2 = __int_as_float(e2.y), m3 = __int_as_float(e3.y);
            float m4 = __int_as_float(e4.y), m5 = __int_as_float(e5.y);
            float m6 = __int_as_float(e6.y), m7 = __int_as_float(e7.y);
            float2 h;
            h = __half22float2(g0); a0 = fmaf(h.x, m0, a0); a1 = fmaf(h.y, m0, a1);
            h = __half22float2(g1); a0 = fmaf(h.x, m1, a0); a1 = fmaf(h.y, m1, a1);
            h = __half22float2(g2); a0 = fmaf(h.x, m2, a0); a1 = fmaf(h.y, m2, a1);
            h = __half22float2(g3); a0 = fmaf(h.x, m3, a0); a1 = fmaf(h.y, m3, a1);
            h = __half22float2(g4); a0 = fmaf(h.x, m4, a0); a1 = fmaf(h.y, m4, a1);
            h = __half22float2(g5); a0 = fmaf(h.x, m5, a0); a1 = fmaf(h.y, m5, a1);
            h = __half22float2(g6); a0 = fmaf(h.x, m6, a0); a1 = fmaf(h.y, m6, a1);
            h = __half22float2(g7); a0 = fmaf(h.x, m7, a0); a1 = fmaf(h.y, m7, a1);
        }
        for (; j + 4 <= j1; j += 4) {
            int2 e0 = se[j], e1 = se[j + 1], e2 = se[j + 2], e3 = se[j + 3];
            int s0 = rfl(e0.x), s1 = rfl(e1.x), s2 = rfl(e2.x), s3 = rfl(e3.x);
            __half2 g0 = ((const __half2*)(Hh + (size_t)s0 * 128))[lane];
            __half2 g1 = ((const __half2*)(Hh + (size_t)s1 * 128))[lane];
            __half2 g2 = ((const __half2*)(Hh + (size_t)s2 * 128))[lane];
            __half2 g3 = ((const __half2*)(Hh + (size_t)s3 * 128))[lane];
            float m0 = __int_as_float(e0.y), m1 = __int_as_float(e1.y);
            float m2 = __int_as_float(e2.y), m3 = __int_as_float(e3.y);
            float2 h;
            h = __half22float2(g0); a0 = fmaf(h.x, m0, a0); a1 = fmaf(h.y, m0, a1);
            h = __half22float2(g1); a0 = fmaf(h.x, m1, a0); a1 = fmaf(h.y, m1, a1);
            h = __half22float2(g2); a0 = fmaf(h.x, m2, a0); a1 = fmaf(h.y, m2, a1);
            h = __half22float2(g3); a0 = fmaf(h.x, m3, a0); a1 = fmaf(h.y, m3, a1);
        }
        for (; j < j1; ++j) {
            int2 e0 = se[j];
            int s0 = rfl(e0.x);
            __half2 g0 = ((const __half2*)(Hh + (size_t)s0 * 128))[lane];
            float m0 = __int_as_float(e0.y);
            float2 h = __half22float2(g0);
            a0 = fmaf(h.x, m0, a0); a1 = fmaf(h.y, m0, a1);
        }
        a0 += bv.x; a1 += bv.y;
        a0 = fmaxf(a0, 0.f); a1 = fmaxf(a1, 0.f);
        if (OUTH) {
            ((__half2*)((__half*)Ov + (size_t)iu * 128))[lane] = __floats2half2_rn(a0, a1);
        } else {
            *(float2*)((float*)Ov + (size_t)iu * 128 + 2 * lane) = make_float2(a0, a1);
        }
    }
}

// parallel partial mean-pool
__global__ __launch_bounds__(256) void k_pool_part(const float* __restrict__ X,
        const int* __restrict__ batch, float* __restrict__ pooled, int N) {
    int c = threadIdx.x & 127, sub = threadIdx.x >> 7;
    int chunk = (N + gridDim.x - 1) / gridDim.x;
    int b = blockIdx.x * chunk, e = min(b + chunk, N);
    float acc = 0.f;
    int cg = -1;
    for (int n = b + sub; n < e; n += 2) {
        int g = batch[n];
        if (g != cg) {
            if (cg >= 0) atomicAdd(&pooled[cg * 128 + c], acc);
            acc = 0.f;
            cg = g;
        }
        acc += X[(size_t)n * 128 + c];
    }
    if (cg >= 0) atomicAdd(&pooled[cg * 128 + c], acc);
}

__global__ void k_final(const float* __restrict__ P, const int* __restrict__ batch,
        const float* __restrict__ Wl, const float* __restrict__ bl,
        float* __restrict__ out, int G, int CO, int N) {
    int t = blockIdx.x * blockDim.x + threadIdx.x;
    if (t >= G * CO) return;
    int g = t / CO, o = t % CO;
    int cnt = lowerb(batch, N, g + 1) - lowerb(batch, N, g);
    float inv = cnt > 0 ? 1.0f / (float)cnt : 0.0f;
    float acc = bl[o];
    for (int k = 0; k < 128; ++k) acc += P[g * 128 + k] * inv * Wl[k * CO + o];
    out[t] = acc;
}

// ---------------- launcher ----------------
extern "C" void kernel_launch(void* const* d_in, const int* in_sizes, int n_in,
                              void* d_out, int out_size, void* d_ws, size_t ws_size,
                              hipStream_t stream) {
    const float* x     = (const float*)d_in[0];
    const int*   ei    = (const int*)d_in[1];
    const int*   batch = (const int*)d_in[2];
    const float* W1e   = (const float*)d_in[5];
    const float* b1e   = (const float*)d_in[6];
    const float* W2e   = (const float*)d_in[9];
    const float* b2e   = (const float*)d_in[10];
    const float* Wlin  = (const float*)d_in[11];
    const float* blin  = (const float*)d_in[12];
    float* out = (float*)d_out;

    int N  = in_sizes[0] / 128;
    int E  = in_sizes[1] / 2;
    int CO = in_sizes[12];          // 10
    int G  = out_size / CO;         // 64

    const int* src = ei;
    const int* dst = ei + E;

    int* deg  = (int*)d_ws;                          // N
    int* off  = deg + N;                             // N+1 (pad 4)
    int* cur  = off + (N + 4);                       // N
    int2* sedge = (int2*)(cur + N);                  // E int2
    float* dinv   = (float*)(sedge + E);             // N
    _Float16* hh  = (_Float16*)(dinv + N);           // N*128 fp16
    _Float16* xh  = hh + (size_t)N * 128;            // N*128 fp16
    float* xbuf   = (float*)(xh + (size_t)N * 128);  // N*128 f32
    float* pooled = xbuf + (size_t)N * 128;          // G*128
    _Float16* wfrag = (_Float16*)(pooled + (size_t)G * 128);  // 16384 halves
    int* locscan  = (int*)(wfrag + 16384);           // N
    int* bsum     = locscan + N;                     // 256
    int* boff     = bsum + 256;                      // 256

    int nb = (N + 255) / 256;

    // XCD-partition chunking: 256 chunks x 8 range-blocks = 2048 blocks
    int nchunks = 256;
    int csz = (E + nchunks - 1) / nchunks;

    k_zero_i32<<<(N + 255) / 256, 256, 0, stream>>>(deg, N);
    k_zero_i32<<<(G * 128 + 255) / 256, 256, 0, stream>>>((int*)pooled, G * 128);
    k_hist_x<<<nchunks * NXCD, 256, 0, stream>>>(dst, deg, E, N, csz);
    k_scan1<<<nb, 256, 0, stream>>>(deg, locscan, bsum, dinv, N);
    k_scan2<<<1, 256, 0, stream>>>(bsum, boff, off, nb, N);
    k_scan3<<<nb, 256, 0, stream>>>(locscan, boff, off, cur, N);
    k_scatter_x<<<nchunks * NXCD, 256, 0, stream>>>(src, dst, cur, sedge, dinv, E, N, csz);

    k_x2h<<<2048, 256, 0, stream>>>(x, xh, N * 32);

    int nstrips = (N + 15) / 16;
    int gemm_blocks = (nstrips * 2 + 3) / 4;

    // layer 1
    k_prep_w<<<1, 256, 0, stream>>>(W1e, wfrag);
    k_gemm_mfma<<<gemm_blocks, 256, 0, stream>>>(xh, wfrag, hh, N);
    k_agg<1><<<2048, 256, 0, stream>>>((const __half*)hh, dinv, off, sedge, b1e, (void*)xh, N);
    // layer 2
    k_prep_w<<<1, 256, 0, stream>>>(W2e, wfrag);
    k_gemm_mfma<<<gemm_blocks, 256, 0, stream>>>(xh, wfrag, hh, N);
    k_agg<0><<<2048, 256, 0, stream>>>((const __half*)hh, dinv, off, sedge, b2e, (void*)xbuf, N);

    k_pool_part<<<512, 256, 0, stream>>>(xbuf, batch, pooled, N);
    k_final<<<3, 256, 0, stream>>>(pooled, batch, Wlin, blin, out, G, CO, N);
}